// Round 1
// baseline (329.749 us; speedup 1.0000x reference)
//
#include <hip/hip_runtime.h>
#include <hip/hip_bf16.h>
#include <stdint.h>

typedef unsigned short u16;
typedef __attribute__((ext_vector_type(8))) short short8;
typedef __attribute__((ext_vector_type(4))) float f32x4;

#define SEQ 2048
#define DIM 1024
#define NBATCH 2
#define MTOT 4096  // NBATCH*SEQ

__device__ __forceinline__ float bf2f(u16 u){
  union { uint32_t i; float f; } c; c.i = ((uint32_t)u) << 16; return c.f;
}
__device__ __forceinline__ u16 f2bf(float f){
  union { float f; uint32_t i; } c; c.f = f;
  uint32_t r = c.i + 0x7FFFu + ((c.i >> 16) & 1u);
  return (u16)(r >> 16);
}

__global__ void fill_kernel(float* p, float v, int n){
  int i = blockIdx.x * 256 + threadIdx.x;
  if (i < n) p[i] = v;
}

// src fp32 -> hi bf16 (+ optional lo = bf16(src - hi))
__global__ void split_kernel(const float* __restrict__ src, u16* __restrict__ hi,
                             u16* __restrict__ lo, int n){
  int i = blockIdx.x * 256 + threadIdx.x;
  if (i >= n) return;
  float v = src[i];
  u16 h = f2bf(v);
  hi[i] = h;
  if (lo) lo[i] = f2bf(v - bf2f(h));
}

// C = sum_seg Aseg @ Bseg^T  (+bias), A:(M,K) row-major, B:(N,K) row-major.
// 128x128 tile, 4 waves, 4x4 16x16x32 MFMA frags per wave, BK=32.
// MODE: 0=f32 out, 1=split hi/lo bf16 out, 2=bf16 out, 3=bf16 transposed (vT) out
template<int MODE>
__global__ __launch_bounds__(256, 2)
void gemm_bt(const u16* __restrict__ A0, const u16* __restrict__ A1, const u16* __restrict__ A2,
             const u16* __restrict__ B0, const u16* __restrict__ B1, const u16* __restrict__ B2,
             int nseg, int Kseg, int lda, int ldb,
             long bsA, long bsB, long bsC,
             float* __restrict__ Cf, u16* __restrict__ Cu0, u16* __restrict__ Cu1,
             const float* __restrict__ bias, int ldc)
{
  __shared__ __align__(16) u16 As[128 * 32];
  __shared__ __align__(16) u16 Bs[128 * 32];
  const int tid  = threadIdx.x;
  const int lane = tid & 63;
  const int wid  = tid >> 6;
  const int bm = blockIdx.x, bn = blockIdx.y, bz = blockIdx.z;

  f32x4 acc[4][4];
#pragma unroll
  for (int i = 0; i < 4; i++)
#pragma unroll
    for (int j = 0; j < 4; j++) acc[i][j] = (f32x4){0.f, 0.f, 0.f, 0.f};

  const int srow = tid >> 2;            // 0..63
  const int scol = (tid & 3) * 8;       // 0,8,16,24
  const int wrow = (wid >> 1) * 64;
  const int wcol = (wid & 1) * 64;
  const int lrow = lane & 15;
  const int lko  = (lane >> 4) * 8;

  const long arowoff = (long)(bm * 128 + srow) * lda + scol;
  const long browoff = (long)(bn * 128 + srow) * ldb + scol;

  for (int seg = 0; seg < nseg; ++seg){
    const u16* Ag = (seg == 0 ? A0 : (seg == 1 ? A1 : A2)) + (long)bz * bsA;
    const u16* Bg = (seg == 0 ? B0 : (seg == 1 ? B1 : B2)) + (long)bz * bsB;
    for (int k0 = 0; k0 < Kseg; k0 += 32){
      __syncthreads();   // prev iter's ds_reads done before overwrite
      const u16* ga = Ag + arowoff + k0;
      const u16* gb = Bg + browoff + k0;
      __builtin_amdgcn_global_load_lds((__attribute__((address_space(1))) void*)ga,
          (__attribute__((address_space(3))) void*)(&As[tid * 8]), 16, 0, 0);
      __builtin_amdgcn_global_load_lds((__attribute__((address_space(1))) void*)(ga + (long)64 * lda),
          (__attribute__((address_space(3))) void*)(&As[2048 + tid * 8]), 16, 0, 0);
      __builtin_amdgcn_global_load_lds((__attribute__((address_space(1))) void*)gb,
          (__attribute__((address_space(3))) void*)(&Bs[tid * 8]), 16, 0, 0);
      __builtin_amdgcn_global_load_lds((__attribute__((address_space(1))) void*)(gb + (long)64 * ldb),
          (__attribute__((address_space(3))) void*)(&Bs[2048 + tid * 8]), 16, 0, 0);
      __syncthreads();   // staging complete (vmcnt drained by barrier)
      short8 af[4], bfr[4];
#pragma unroll
      for (int i = 0; i < 4; i++)
        af[i] = *(const short8*)&As[(wrow + i * 16 + lrow) * 32 + lko];
#pragma unroll
      for (int j = 0; j < 4; j++)
        bfr[j] = *(const short8*)&Bs[(wcol + j * 16 + lrow) * 32 + lko];
#pragma unroll
      for (int i = 0; i < 4; i++)
#pragma unroll
        for (int j = 0; j < 4; j++)
          acc[i][j] = __builtin_amdgcn_mfma_f32_16x16x32_bf16(af[i], bfr[j], acc[i][j], 0, 0, 0);
    }
  }

  // Epilogue. C/D frag layout (m89-verified): col = lane&15, row = (lane>>4)*4 + reg
  const int cc = lane & 15;
  const int rr = (lane >> 4) * 4;
#pragma unroll
  for (int i = 0; i < 4; i++){
#pragma unroll
    for (int j = 0; j < 4; j++){
      const int col = bn * 128 + wcol + j * 16 + cc;
      const float badd = bias ? bias[col] : 0.f;
#pragma unroll
      for (int r = 0; r < 4; r++){
        const int row = bm * 128 + wrow + i * 16 + rr + r;
        float v = acc[i][j][r] + badd;
        if constexpr (MODE == 0){
          Cf[(long)bz * bsC + (long)row * ldc + col] = v;
        } else if constexpr (MODE == 1){
          u16 h = f2bf(v);
          Cu0[(long)row * ldc + col] = h;
          Cu1[(long)row * ldc + col] = f2bf(v - bf2f(h));
        } else if constexpr (MODE == 2){
          Cu0[(long)bz * bsC + (long)row * ldc + col] = f2bf(v);
        } else {  // vT[b][d][t], b = row>>11, t = row&2047, d = col
          const int b2 = row >> 11, t = row & 2047;
          Cu0[(long)b2 * DIM * SEQ + (long)col * SEQ + t] = f2bf(v);
        }
      }
    }
  }
}

// One block per row: theta(qk) -> softmax -> bf16 attn. Row of 2048 held in regs.
__global__ __launch_bounds__(256)
void softmax_kernel(const float* __restrict__ qk, u16* __restrict__ attn){
  const long row = blockIdx.x;
  const float* src = qk + row * SEQ;
  u16* dst = attn + row * SEQ;
  const int tid = threadIdx.x;
  float th[8];
  float mx = -1e30f;
#pragma unroll
  for (int j = 0; j < 8; j++){
    float x = src[tid + j * 256];
    float sg = 1.f / (1.f + __expf(-x));
    float t = 0.5f + 0.2f * sg + 0.15f * tanhf(x) + 0.1f * fmaxf(x, 0.f);
    th[j] = t;
    mx = fmaxf(mx, t);
  }
#pragma unroll
  for (int o = 32; o > 0; o >>= 1) mx = fmaxf(mx, __shfl_xor(mx, o, 64));
  __shared__ float redm[4], reds[4];
  const int wv = tid >> 6;
  if ((tid & 63) == 0) redm[wv] = mx;
  __syncthreads();
  mx = fmaxf(fmaxf(redm[0], redm[1]), fmaxf(redm[2], redm[3]));
  float p[8]; float sum = 0.f;
#pragma unroll
  for (int j = 0; j < 8; j++){ p[j] = __expf(th[j] - mx); sum += p[j]; }
#pragma unroll
  for (int o = 32; o > 0; o >>= 1) sum += __shfl_xor(sum, o, 64);
  if ((tid & 63) == 0) reds[wv] = sum;
  __syncthreads();
  sum = reds[0] + reds[1] + reds[2] + reds[3];
  const float inv = 1.f / sum;
#pragma unroll
  for (int j = 0; j < 8; j++) dst[tid + j * 256] = f2bf(p[j] * inv);
}

extern "C" void kernel_launch(void* const* d_in, const int* in_sizes, int n_in,
                              void* d_out, int out_size, void* d_ws, size_t ws_size,
                              hipStream_t stream){
  const float* x  = (const float*)d_in[0];
  const float* Wq = (const float*)d_in[1];
  const float* bq = (const float*)d_in[2];
  const float* Wk = (const float*)d_in[3];
  const float* bk = (const float*)d_in[4];
  const float* Wv = (const float*)d_in[5];
  const float* bv = (const float*)d_in[6];
  const float* Wo = (const float*)d_in[7];
  const float* bo = (const float*)d_in[8];
  float* out = (float*)d_out;

  char* ws = (char*)d_ws;
  size_t off = 0;
  auto alloc = [&](size_t bytes) -> char* {
    char* p = ws + off; off += (bytes + 255) & ~(size_t)255; return p;
  };

  float* qkbuf = (float*)alloc(sizeof(float) * (size_t)NBATCH * SEQ * SEQ);  // 33.5 MB
  u16* q_hi  = (u16*)alloc(2ull * MTOT * DIM);
  u16* q_lo  = (u16*)alloc(2ull * MTOT * DIM);
  u16* k_hi  = (u16*)alloc(2ull * MTOT * DIM);
  u16* k_lo  = (u16*)alloc(2ull * MTOT * DIM);
  u16* vT    = (u16*)alloc(2ull * NBATCH * DIM * SEQ);
  u16* Wq_hi = (u16*)alloc(2ull * DIM * DIM);
  u16* Wq_lo = (u16*)alloc(2ull * DIM * DIM);
  u16* Wk_hi = (u16*)alloc(2ull * DIM * DIM);
  u16* Wk_lo = (u16*)alloc(2ull * DIM * DIM);
  u16* Wv_hi = (u16*)alloc(2ull * DIM * DIM);
  u16* Wo_hi = (u16*)alloc(2ull * DIM * DIM);
  u16* x_hi  = (u16*)alloc(2ull * MTOT * DIM);
  u16* x_lo  = (u16*)alloc(2ull * MTOT * DIM);
  u16* attn  = x_hi;   // alias: x region free after projections
  u16* outb  = q_hi;   // alias: q region free after qk

  if (off > ws_size){
    fill_kernel<<<(out_size + 255) / 256, 256, 0, stream>>>(out, 12345.0f, out_size);
    return;
  }

  const int nx = MTOT * DIM, nw = DIM * DIM;
  split_kernel<<<(nx + 255) / 256, 256, 0, stream>>>(x,  x_hi, x_lo, nx);
  split_kernel<<<(nw + 255) / 256, 256, 0, stream>>>(Wq, Wq_hi, Wq_lo, nw);
  split_kernel<<<(nw + 255) / 256, 256, 0, stream>>>(Wk, Wk_hi, Wk_lo, nw);
  split_kernel<<<(nw + 255) / 256, 256, 0, stream>>>(Wv, Wv_hi, nullptr, nw);
  split_kernel<<<(nw + 255) / 256, 256, 0, stream>>>(Wo, Wo_hi, nullptr, nw);

  // q = x@Wq^T (compensated: xh*Wh + xl*Wh + xh*Wl), split epilogue
  gemm_bt<1><<<dim3(MTOT / 128, DIM / 128, 1), 256, 0, stream>>>(
      x_hi, x_lo, x_hi, Wq_hi, Wq_hi, Wq_lo, 3, DIM, DIM, DIM,
      0, 0, 0, nullptr, q_hi, q_lo, bq, DIM);
  // k
  gemm_bt<1><<<dim3(MTOT / 128, DIM / 128, 1), 256, 0, stream>>>(
      x_hi, x_lo, x_hi, Wk_hi, Wk_hi, Wk_lo, 3, DIM, DIM, DIM,
      0, 0, 0, nullptr, k_hi, k_lo, bk, DIM);
  // v (plain bf16, transposed epilogue -> vT[b][d][t])
  gemm_bt<3><<<dim3(MTOT / 128, DIM / 128, 1), 256, 0, stream>>>(
      x_hi, nullptr, nullptr, Wv_hi, nullptr, nullptr, 1, DIM, DIM, DIM,
      0, 0, 0, nullptr, vT, nullptr, bv, 0);
  // qk = q@k^T per batch (compensated), fp32 out
  gemm_bt<0><<<dim3(SEQ / 128, SEQ / 128, NBATCH), 256, 0, stream>>>(
      q_hi, q_lo, q_hi, k_hi, k_hi, k_lo, 3, DIM, DIM, DIM,
      (long)SEQ * DIM, (long)SEQ * DIM, (long)SEQ * SEQ,
      qkbuf, nullptr, nullptr, nullptr, SEQ);
  // theta + softmax -> bf16 attn
  softmax_kernel<<<NBATCH * SEQ, 256, 0, stream>>>(qkbuf, attn);
  // out = attn @ v  (B-operand = vT, K-contiguous)
  gemm_bt<2><<<dim3(SEQ / 128, DIM / 128, NBATCH), 256, 0, stream>>>(
      attn, nullptr, nullptr, vT, nullptr, nullptr, 1, SEQ, SEQ, SEQ,
      (long)SEQ * SEQ, (long)DIM * SEQ, (long)SEQ * DIM,
      nullptr, outb, nullptr, nullptr, DIM);
  // y = out @ Wo^T + bo, fp32 to d_out
  gemm_bt<0><<<dim3(MTOT / 128, DIM / 128, 1), 256, 0, stream>>>(
      outb, nullptr, nullptr, Wo_hi, nullptr, nullptr, 1, DIM, DIM, DIM,
      0, 0, 0, out, nullptr, nullptr, bo, DIM);
}

// Round 2
// 176.619 us; speedup vs baseline: 1.8670x; 1.8670x over previous
//
#include <hip/hip_runtime.h>
#include <hip/hip_fp16.h>
#include <stdint.h>

typedef unsigned short u16;
typedef _Float16 f16;
typedef __attribute__((ext_vector_type(8))) _Float16 f16x8;
typedef __attribute__((ext_vector_type(4))) _Float16 f16x4;
typedef __attribute__((ext_vector_type(4))) float f32x4;

#define SEQ 2048
#define DIM 1024
#define NBATCH 2
#define MTOT 4096  // NBATCH*SEQ

__global__ void fill_kernel(float* p, float v, int n){
  int i = blockIdx.x * 256 + threadIdx.x;
  if (i < n) p[i] = v;
}

// x (4M floats) -> fp16, 4 elems/thread
__global__ void cvt_x_kernel(const float* __restrict__ src, f16* __restrict__ dst){
  int i = blockIdx.x * 256 + threadIdx.x;
  float4 v = ((const float4*)src)[i];
  ((f16x4*)dst)[i] = (f16x4){(f16)v.x, (f16)v.y, (f16)v.z, (f16)v.w};
}

// Wq,Wk,Wv -> Wcat (3072x1024 fp16), Wo -> Wo16. 1024 blocks per tensor.
__global__ void cvt_w_kernel(const float* __restrict__ Wq, const float* __restrict__ Wk,
                             const float* __restrict__ Wv, const float* __restrict__ Wo,
                             f16* __restrict__ Wcat, f16* __restrict__ Wo16){
  int b = blockIdx.x;
  int t = b >> 10;                       // tensor id 0..3
  int i = (b & 1023) * 256 + threadIdx.x;  // float4 index within tensor
  const float* src = t == 0 ? Wq : t == 1 ? Wk : t == 2 ? Wv : Wo;
  f16* dst = (t == 3) ? Wo16 : Wcat + (size_t)t * DIM * DIM;
  float4 v = ((const float4*)src)[i];
  ((f16x4*)dst)[i] = (f16x4){(f16)v.x, (f16)v.y, (f16)v.z, (f16)v.w};
}

// C = A @ B^T (+bias). A:(M,K) row-major fp16, B:(N,K) row-major fp16.
// 128x128 tile, 4 waves, 4x4 16x16x32 MFMA frags, BK=32 (m97 structure).
// MODE 0: fp32 out (+bias0)        -> Cf
// MODE 2: fp16 out (+bias0)        -> Ch
// MODE 4: fused qkv epilogue: col<2048 -> Ch (q|k cat, ldc), col>=2048 -> vT[b][d][t]
template<int MODE>
__global__ __launch_bounds__(256, 2)
void gemm_bt(const f16* __restrict__ A, const f16* __restrict__ B,
             int K, int lda, int ldb, long bsA, long bsB, long bsC,
             float* __restrict__ Cf, f16* __restrict__ Ch, f16* __restrict__ vT,
             const float* __restrict__ bias0, const float* __restrict__ bias1,
             const float* __restrict__ bias2, int ldc)
{
  __shared__ __align__(16) f16 As[128 * 32];
  __shared__ __align__(16) f16 Bs[128 * 32];
  const int tid  = threadIdx.x;
  const int lane = tid & 63;
  const int wid  = tid >> 6;
  const int bm = blockIdx.x, bn = blockIdx.y, bz = blockIdx.z;

  f32x4 acc[4][4];
#pragma unroll
  for (int i = 0; i < 4; i++)
#pragma unroll
    for (int j = 0; j < 4; j++) acc[i][j] = (f32x4){0.f, 0.f, 0.f, 0.f};

  const int srow = tid >> 2;            // 0..63
  const int scol = (tid & 3) * 8;       // 0,8,16,24
  const int wrow = (wid >> 1) * 64;
  const int wcol = (wid & 1) * 64;
  const int lrow = lane & 15;
  const int lko  = (lane >> 4) * 8;

  const f16* Ag = A + (long)bz * bsA + (long)(bm * 128 + srow) * lda + scol;
  const f16* Bg = B + (long)bz * bsB + (long)(bn * 128 + srow) * ldb + scol;

  for (int k0 = 0; k0 < K; k0 += 32){
    __syncthreads();   // prev iter's ds_reads done before overwrite
    const f16* ga = Ag + k0;
    const f16* gb = Bg + k0;
    __builtin_amdgcn_global_load_lds((__attribute__((address_space(1))) void*)ga,
        (__attribute__((address_space(3))) void*)(&As[tid * 8]), 16, 0, 0);
    __builtin_amdgcn_global_load_lds((__attribute__((address_space(1))) void*)(ga + (long)64 * lda),
        (__attribute__((address_space(3))) void*)(&As[2048 + tid * 8]), 16, 0, 0);
    __builtin_amdgcn_global_load_lds((__attribute__((address_space(1))) void*)gb,
        (__attribute__((address_space(3))) void*)(&Bs[tid * 8]), 16, 0, 0);
    __builtin_amdgcn_global_load_lds((__attribute__((address_space(1))) void*)(gb + (long)64 * ldb),
        (__attribute__((address_space(3))) void*)(&Bs[2048 + tid * 8]), 16, 0, 0);
    __syncthreads();   // staging complete (barrier drains vmcnt)
    f16x8 af[4], bfr[4];
#pragma unroll
    for (int i = 0; i < 4; i++)
      af[i] = *(const f16x8*)&As[(wrow + i * 16 + lrow) * 32 + lko];
#pragma unroll
    for (int j = 0; j < 4; j++)
      bfr[j] = *(const f16x8*)&Bs[(wcol + j * 16 + lrow) * 32 + lko];
#pragma unroll
    for (int i = 0; i < 4; i++)
#pragma unroll
      for (int j = 0; j < 4; j++)
        acc[i][j] = __builtin_amdgcn_mfma_f32_16x16x32_f16(af[i], bfr[j], acc[i][j], 0, 0, 0);
  }

  // Epilogue. C/D layout (m89-verified): col = lane&15, row = (lane>>4)*4 + reg
  const int cc = lane & 15;
  const int rr = (lane >> 4) * 4;
#pragma unroll
  for (int i = 0; i < 4; i++){
#pragma unroll
    for (int j = 0; j < 4; j++){
      const int col = bn * 128 + wcol + j * 16 + cc;
#pragma unroll
      for (int r = 0; r < 4; r++){
        const int row = bm * 128 + wrow + i * 16 + rr + r;
        float v = acc[i][j][r];
        if constexpr (MODE == 0){
          if (bias0) v += bias0[col];
          Cf[(long)bz * bsC + (long)row * ldc + col] = v;
        } else if constexpr (MODE == 2){
          if (bias0) v += bias0[col];
          Ch[(long)bz * bsC + (long)row * ldc + col] = (f16)v;
        } else {  // MODE 4: fused q|k|v epilogue
          if (col < 2048){
            v += (col < 1024) ? bias0[col] : bias1[col - 1024];
            Ch[(long)row * ldc + col] = (f16)v;
          } else {
            v += bias2[col - 2048];
            const int b2 = row >> 11, t = row & 2047;
            vT[(long)b2 * DIM * SEQ + (long)(col - 2048) * SEQ + t] = (f16)v;
          }
        }
      }
    }
  }
}

// One block per row: theta(qk) -> softmax -> fp16 attn. Row of 2048 in regs.
__global__ __launch_bounds__(256)
void softmax_kernel(const float* __restrict__ qk, f16* __restrict__ attn){
  const long row = blockIdx.x;
  const float* src = qk + row * SEQ;
  f16* dst = attn + row * SEQ;
  const int tid = threadIdx.x;
  float th[8];
  float mx = -1e30f;
#pragma unroll
  for (int j = 0; j < 8; j++){
    float x = src[tid + j * 256];
    float sg = 1.f / (1.f + __expf(-x));
    float t = 0.5f + 0.2f * sg + 0.15f * tanhf(x) + 0.1f * fmaxf(x, 0.f);
    th[j] = t;
    mx = fmaxf(mx, t);
  }
#pragma unroll
  for (int o = 32; o > 0; o >>= 1) mx = fmaxf(mx, __shfl_xor(mx, o, 64));
  __shared__ float redm[4], reds[4];
  const int wv = tid >> 6;
  if ((tid & 63) == 0) redm[wv] = mx;
  __syncthreads();
  mx = fmaxf(fmaxf(redm[0], redm[1]), fmaxf(redm[2], redm[3]));
  float p[8]; float sum = 0.f;
#pragma unroll
  for (int j = 0; j < 8; j++){ p[j] = __expf(th[j] - mx); sum += p[j]; }
#pragma unroll
  for (int o = 32; o > 0; o >>= 1) sum += __shfl_xor(sum, o, 64);
  if ((tid & 63) == 0) reds[wv] = sum;
  __syncthreads();
  sum = reds[0] + reds[1] + reds[2] + reds[3];
  const float inv = 1.f / sum;
#pragma unroll
  for (int j = 0; j < 8; j++) dst[tid + j * 256] = (f16)(p[j] * inv);
}

extern "C" void kernel_launch(void* const* d_in, const int* in_sizes, int n_in,
                              void* d_out, int out_size, void* d_ws, size_t ws_size,
                              hipStream_t stream){
  const float* x  = (const float*)d_in[0];
  const float* Wq = (const float*)d_in[1];
  const float* bq = (const float*)d_in[2];
  const float* Wk = (const float*)d_in[3];
  const float* bk = (const float*)d_in[4];
  const float* Wv = (const float*)d_in[5];
  const float* bv = (const float*)d_in[6];
  const float* Wo = (const float*)d_in[7];
  const float* bo = (const float*)d_in[8];
  float* out = (float*)d_out;

  char* ws = (char*)d_ws;
  size_t off = 0;
  auto alloc = [&](size_t bytes) -> char* {
    char* p = ws + off; off += (bytes + 255) & ~(size_t)255; return p;
  };

  float* qkbuf = (float*)alloc(sizeof(float) * (size_t)NBATCH * SEQ * SEQ);  // 33.5 MB
  f16* x16   = (f16*)alloc(2ull * MTOT * DIM);          // 8 MB
  f16* Wcat  = (f16*)alloc(2ull * 3 * DIM * DIM);       // 6 MB  [Wq;Wk;Wv]
  f16* Wo16  = (f16*)alloc(2ull * DIM * DIM);           // 2 MB
  f16* qkcat = (f16*)alloc(2ull * MTOT * 2 * DIM);      // 16 MB [q|k] per row
  f16* vT    = (f16*)alloc(2ull * NBATCH * DIM * SEQ);  // 8 MB  [b][d][t]
  f16* attn  = (f16*)alloc(2ull * NBATCH * SEQ * SEQ);  // 16 MB
  f16* outb  = (f16*)alloc(2ull * MTOT * DIM);          // 8 MB

  if (off > ws_size){
    fill_kernel<<<(out_size + 255) / 256, 256, 0, stream>>>(out, 12345.0f, out_size);
    return;
  }

  cvt_x_kernel<<<MTOT * DIM / 4 / 256, 256, 0, stream>>>(x, x16);
  cvt_w_kernel<<<4 * DIM * DIM / 4 / 256, 256, 0, stream>>>(Wq, Wk, Wv, Wo, Wcat, Wo16);

  // fused [q|k|vT] = x @ [Wq;Wk;Wv]^T + bias   (25.8 GF, grid 32x24 = 768 blocks)
  gemm_bt<4><<<dim3(MTOT / 128, 3 * DIM / 128, 1), 256, 0, stream>>>(
      x16, Wcat, DIM, DIM, DIM, 0, 0, 0,
      nullptr, qkcat, vT, bq, bk, bv, 2 * DIM);

  // qk = q @ k^T per batch, fp32 out  (17.2 GF, grid 16x16x2)
  gemm_bt<0><<<dim3(SEQ / 128, SEQ / 128, NBATCH), 256, 0, stream>>>(
      qkcat, qkcat + DIM, DIM, 2 * DIM, 2 * DIM,
      (long)SEQ * 2 * DIM, (long)SEQ * 2 * DIM, (long)SEQ * SEQ,
      qkbuf, nullptr, nullptr, nullptr, nullptr, nullptr, SEQ);

  // theta + softmax -> fp16 attn
  softmax_kernel<<<NBATCH * SEQ, 256, 0, stream>>>(qkbuf, attn);

  // out = attn @ v   (B-operand = vT, K-contiguous; 17.2 GF, grid 16x8x2)
  gemm_bt<2><<<dim3(SEQ / 128, DIM / 128, NBATCH), 256, 0, stream>>>(
      attn, vT, SEQ, SEQ, SEQ,
      (long)SEQ * SEQ, (long)DIM * SEQ, (long)SEQ * DIM,
      nullptr, outb, nullptr, nullptr, nullptr, nullptr, DIM);

  // y = out @ Wo^T + bo, fp32 to d_out  (8.6 GF, grid 32x8)
  gemm_bt<0><<<dim3(MTOT / 128, DIM / 128, 1), 256, 0, stream>>>(
      outb, Wo16, DIM, DIM, DIM, 0, 0, 0,
      out, nullptr, nullptr, bo, nullptr, nullptr, DIM);
}